// Round 8
// baseline (189.670 us; speedup 1.0000x reference)
//
#include <hip/hip_runtime.h>
#include <hip/hip_bf16.h>
#include <float.h>

#define NF 75
#define HID 128
#define NB 50
#define NT 12
#define BN_EPS 1e-3f
#define NSEG 64
#define ROWB 656   // LDS A-tile row stride in bytes

typedef __attribute__((ext_vector_type(8))) short short8;
typedef __attribute__((ext_vector_type(4))) float f32x4;

// Static device scratch. Fully written before read on every launch.
__device__ float g_bn1[(size_t)200000 * HID];            // 102.4 MB
__device__ float g_xp[(size_t)200000 * 80];              // padded X, 64 MB
__device__ float g_part[NSEG * NB * 256];                // segment partials
__device__ unsigned short g_wfrag[11 * 5 * 8 * 64 * 16]; // frag-ordered W, hi/lo bf16

struct AdjPtrs { const int* p[10]; };

__device__ __forceinline__ unsigned short f2bf(float x) {
    union { float f; unsigned u; } a; a.f = x;
    unsigned r = a.u + 0x7fffu + ((a.u >> 16) & 1u);   // RTNE
    return (unsigned short)(r >> 16);
}
__device__ __forceinline__ float bf2f(unsigned short h) {
    union { unsigned u; float f; } a; a.u = ((unsigned)h) << 16; return a.f;
}
__device__ __forceinline__ float fast_tanh(float x) {
    float e = __expf(2.f * x);
    return 1.f - 2.f / (e + 1.f);
}

__device__ constexpr int DS_[12] = {0,1000,20000,60000,120000,170000,185000,193000,197000,199000,199700,200000};

// ---------------- K_pre: merged W-conversion (blocks 0..439) + X-pad (blocks 440..3564) ----------------
__global__ __launch_bounds__(256) void k_pre(const float* __restrict__ W, const float* __restrict__ X) {
    if (blockIdx.x < 440) {
        if (threadIdx.x >= 64) return;
        const int id = blockIdx.x;                 // deg*40 + kt*8 + nt
        const int deg = id / 40, kt = (id / 8) % 5, nt = id % 8;
        const int lane = threadIdx.x;
        const int c  = nt * 16 + (lane & 15);
        const int kb = kt * 32 + (lane >> 4) * 8;
        unsigned short hs[8], ls[8];
#pragma unroll
        for (int i = 0; i < 8; ++i) {
            const int k = kb + i;
            float v = 0.f;
            if (deg > 0) {
                if (k < 75)                  v = W[(size_t)(2 * (deg - 1)) * NF * HID + (size_t)k * HID + c];
                else if (k >= 80 && k < 155) v = W[(size_t)(2 * (deg - 1) + 1) * NF * HID + (size_t)(k - 80) * HID + c];
            } else {
                if (k >= 80 && k < 155)      v = W[(size_t)20 * NF * HID + (size_t)(k - 80) * HID + c];
            }
            const unsigned short h = f2bf(v);
            hs[i] = h;
            ls[i] = f2bf(v - bf2f(h));
        }
        unsigned short* dst = g_wfrag + ((size_t)id * 64 + lane) * 16;
#pragma unroll
        for (int i = 0; i < 8; ++i) { dst[i] = hs[i]; dst[8 + i] = ls[i]; }
    } else {
        const int blk = blockIdx.x - 440;
        __shared__ float T[64 * 75];
        const f32x4* src = (const f32x4*)(X + (size_t)blk * 4800);
        for (int i = threadIdx.x; i < 1200; i += 256) {
            const f32x4 t = __builtin_nontemporal_load(&src[i]);  // X read once
            *(f32x4*)&T[i * 4] = t;
        }
        __syncthreads();
        f32x4* dst = (f32x4*)(g_xp + (size_t)blk * 5120);
        for (int o = threadIdx.x; o < 1280; o += 256) {
            const int row = o / 20, f0 = (o % 20) * 4;
            f32x4 r;
            r.x = (f0 + 0 < 75) ? T[row * 75 + f0 + 0] : 0.f;
            r.y = (f0 + 1 < 75) ? T[row * 75 + f0 + 1] : 0.f;
            r.z = (f0 + 2 < 75) ? T[row * 75 + f0 + 2] : 0.f;
            r.w = (f0 + 3 < 75) ? T[row * 75 + f0 + 3] : 0.f;
            dst[o] = r;                                            // normal store: want L3-resident
        }
    }
}

// ---------------- K1: gc1 via MFMA, pipelined gather, nt bn1 stores ----------------
// 512 threads = 8 waves. Staging: thread (lane, wid) fills chunk k0=j*32+wid*4 of row=lane.
// Row layout (ROWB=656B): kt*128 + g*32 + {hi 16B | lo 16B}.
// MFMA: wave wid owns cols [wid*16,wid*16+16); A row=(l&15)+16m, k=(l>>4)*8+i.
template<int DEG>
__device__ __forceinline__ void gc1_body(
    int tile, char* __restrict__ A,
    const float* __restrict__ B,
    const float* __restrict__ bg, const float* __restrict__ bb,
    const float* __restrict__ bm, const float* __restrict__ bv,
    const int* __restrict__ adjBase)
{
    const int dStart = DS_[DEG], dEnd = DS_[DEG + 1];
    const int atom0  = dStart + tile * 64;
    const int nA     = min(64, dEnd - atom0);
    const int tid    = threadIdx.x;
    const int lane   = tid & 63;
    const int wid    = tid >> 6;

    constexpr int NR = (DEG > 0) ? DEG : 1;
    int adjr[NR];
    if (DEG > 0) {
        const int arow = (lane < nA) ? (atom0 + lane - dStart) : 0;
#pragma unroll
        for (int n = 0; n < DEG; ++n)
            adjr[n] = adjBase[(size_t)arow * DEG + n];
    }

    char* wbase = A + lane * ROWB + (wid >> 1) * 32 + (wid & 1) * 8;

    auto issue = [&](int jj, f32x4* t) {
        const int k0 = jj * 32 + wid * 4;          // wave-uniform branch selector
        if (k0 < 80) {
            if (DEG > 0) {
#pragma unroll
                for (int n = 0; n < DEG; ++n)
                    t[n] = *(const f32x4*)(g_xp + (size_t)adjr[n] * 80 + k0);
            } else {
                t[0] = (f32x4){0.f, 0.f, 0.f, 0.f};
            }
        } else {
            if (lane < nA)
                t[0] = *(const f32x4*)(g_xp + (size_t)(atom0 + lane) * 80 + (k0 - 80));
            else
                t[0] = (f32x4){0.f, 0.f, 0.f, 0.f};
        }
    };
    auto finish = [&](int jj, f32x4* t) {
        const int k0 = jj * 32 + wid * 4;
        f32x4 v = t[0];
        if (k0 < 80 && DEG > 1) {
#pragma unroll
            for (int n = 1; n < DEG; ++n) v += t[n];
        }
        if (k0 < 80 && DEG > 0 && lane >= nA) v = (f32x4){0.f, 0.f, 0.f, 0.f};
        unsigned long long hp = 0, lp = 0;
#pragma unroll
        for (int ii = 0; ii < 4; ++ii) {
            const unsigned short h = f2bf(v[ii]);
            const unsigned short l = f2bf(v[ii] - bf2f(h));
            hp |= (unsigned long long)h << (16 * ii);
            lp |= (unsigned long long)l << (16 * ii);
        }
        *(unsigned long long*)(wbase + jj * 128)      = hp;
        *(unsigned long long*)(wbase + jj * 128 + 16) = lp;
    };

    if constexpr (DEG <= 4) {
        // depth-2 software pipeline, fully unrolled (static reg indexing)
        f32x4 tA[NR], tB[NR];
        issue(0, tA);
#pragma unroll
        for (int j = 0; j < 5; ++j) {
            f32x4* cur = (j & 1) ? tB : tA;
            f32x4* nxt = (j & 1) ? tA : tB;
            if (j < 4) issue(j + 1, nxt);
            finish(j, cur);
        }
    } else {
#pragma unroll 1
        for (int j = 0; j < 5; ++j) {
            f32x4 t[NR];
            issue(j, t);
            finish(j, t);
        }
    }
    __syncthreads();

    f32x4 acc[4] = {};
    const int gk = lane >> 4;
    const int kt0 = (DEG == 0) ? 2 : 0;
#pragma unroll
    for (int kt = kt0; kt < 5; ++kt) {
        const unsigned short* wp = g_wfrag + ((size_t)(((DEG * 5 + kt) * 8 + wid) * 64 + lane)) * 16;
        const short8 wh = *(const short8*)wp;
        const short8 wl = *(const short8*)(wp + 8);
#pragma unroll
        for (int m = 0; m < 4; ++m) {
            const char* ab = A + (m * 16 + (lane & 15)) * ROWB + kt * 128 + gk * 32;
            const short8 ah = *(const short8*)ab;
            const short8 al = *(const short8*)(ab + 16);
            acc[m] = __builtin_amdgcn_mfma_f32_16x16x32_bf16(ah, wh, acc[m], 0, 0, 0);
            acc[m] = __builtin_amdgcn_mfma_f32_16x16x32_bf16(al, wh, acc[m], 0, 0, 0);
            acc[m] = __builtin_amdgcn_mfma_f32_16x16x32_bf16(ah, wl, acc[m], 0, 0, 0);
        }
    }

    const int col = wid * 16 + (lane & 15);
    const float bsum = (DEG > 0)
        ? (B[(size_t)(2 * (DEG - 1)) * HID + col] + B[(size_t)(2 * (DEG - 1) + 1) * HID + col])
        : B[(size_t)20 * HID + col];
    const float s  = bg[col] * rsqrtf(bv[col] + BN_EPS);
    const float sh = bb[col] - bm[col] * s;
#pragma unroll
    for (int m = 0; m < 4; ++m) {
#pragma unroll
        for (int j = 0; j < 4; ++j) {
            const int r = m * 16 + (lane >> 4) * 4 + j;
            if (r < nA) {
                const float val = fast_tanh(acc[m][j] + bsum) * s + sh;
                __builtin_nontemporal_store(val, &g_bn1[(size_t)(atom0 + r) * HID + col]);
            }
        }
    }
}

__global__ __launch_bounds__(512, 6) void k_gc1(
    const float* __restrict__ B,
    const float* __restrict__ bg, const float* __restrict__ bb,
    const float* __restrict__ bm, const float* __restrict__ bv,
    AdjPtrs adj)
{
    // heavy-first: deg 10,9,...,1,0
    constexpr int TSH[12]    = {0,5,16,48,111,236,471,1253,2191,2816,3113,3129};
    constexpr int DEGORD[11] = {10,9,8,7,6,5,4,3,2,1,0};
    __shared__ __align__(16) char A[64 * ROWB];   // 41.98 KB -> 3 blocks/CU

    const int blk = blockIdx.x;
    int seg = 0;
#pragma unroll
    for (int s = 1; s <= 10; ++s) if (blk >= TSH[s]) seg = s;
    const int deg  = DEGORD[seg];
    const int tile = blk - TSH[seg];

    switch (deg) {
        case 0:  gc1_body<0 >(tile, A, B, bg, bb, bm, bv, nullptr);   break;
        case 1:  gc1_body<1 >(tile, A, B, bg, bb, bm, bv, adj.p[0]);  break;
        case 2:  gc1_body<2 >(tile, A, B, bg, bb, bm, bv, adj.p[1]);  break;
        case 3:  gc1_body<3 >(tile, A, B, bg, bb, bm, bv, adj.p[2]);  break;
        case 4:  gc1_body<4 >(tile, A, B, bg, bb, bm, bv, adj.p[3]);  break;
        case 5:  gc1_body<5 >(tile, A, B, bg, bb, bm, bv, adj.p[4]);  break;
        case 6:  gc1_body<6 >(tile, A, B, bg, bb, bm, bv, adj.p[5]);  break;
        case 7:  gc1_body<7 >(tile, A, B, bg, bb, bm, bv, adj.p[6]);  break;
        case 8:  gc1_body<8 >(tile, A, B, bg, bb, bm, bv, adj.p[7]);  break;
        case 9:  gc1_body<9 >(tile, A, B, bg, bb, bm, bv, adj.p[8]);  break;
        case 10: gc1_body<10>(tile, A, B, bg, bb, bm, bv, adj.p[9]);  break;
    }
}

// ---------------- K2: deterministic segment sum/max partials ----------------
__global__ __launch_bounds__(128) void k_seg(const int* __restrict__ memb)
{
    const int b = blockIdx.x % NB;
    const int s = blockIdx.x / NB;
    const int aLo = s * (200000 / NSEG);
    const int aHi = aLo + (200000 / NSEG);
    const int wave = threadIdx.x >> 6;
    const int lane = threadIdx.x & 63;

    __shared__ int q[2][256];
    __shared__ int qn[2];
    int* myq = q[wave];
    int nq = 0;

    for (int base = aLo + wave * 64; base < aHi; base += 128) {
        const int a = base + lane;
        const bool m = (a < aHi) && (memb[a] == b);
        const unsigned long long bal = __ballot(m);
        if (m) {
            const int pos = __popcll(bal & ((1ull << lane) - 1ull));
            if (nq + pos < 256) myq[nq + pos] = a;
        }
        nq += __popcll(bal);
    }
    if (lane == 0) qn[wave] = min(nq, 256);
    __syncthreads();

    const int c = threadIdx.x;  // col 0..127
    float sum = 0.f, mx = -FLT_MAX;
#pragma unroll
    for (int w2 = 0; w2 < 2; ++w2) {
        const int n = qn[w2];
        for (int i = 0; i < n; ++i) {
            const float v = __builtin_nontemporal_load(&g_bn1[(size_t)q[w2][i] * HID + c]);
            sum += v;
            mx = fmaxf(mx, v);
        }
    }
    float* pd = g_part + (size_t)(s * NB + b) * 256;
    pd[c] = sum;
    pd[128 + c] = mx;
}

// ---------------- K3: reduce partials, tanh, dense [256,24], softmax pairs ----------------
__global__ __launch_bounds__(256) void k_final(const float* __restrict__ W2,
                                               const float* __restrict__ b2,
                                               float* __restrict__ out)
{
    const int b = blockIdx.x;
    const int t = threadIdx.x;
    __shared__ float ro[256];
    __shared__ float lg[24];

    {
        float v;
        if (t < 128) {
            float sv = 0.f;
            for (int s = 0; s < NSEG; ++s) sv += g_part[(size_t)(s * NB + b) * 256 + t];
            v = sv;
        } else {
            float mv = -FLT_MAX;
            for (int s = 0; s < NSEG; ++s) mv = fmaxf(mv, g_part[(size_t)(s * NB + b) * 256 + t]);
            v = mv;
        }
        ro[t] = tanhf(v);
    }
    __syncthreads();
    if (t < 24) {
        float acc = b2[t];
        for (int c = 0; c < 256; ++c) acc = fmaf(ro[c], W2[c * 24 + t], acc);
        lg[t] = acc;
    }
    __syncthreads();
    if (t < NT) {
        const float l0 = lg[2 * t], l1 = lg[2 * t + 1];
        const float m = fmaxf(l0, l1);
        const float e0 = expf(l0 - m), e1 = expf(l1 - m);
        const float inv = 1.f / (e0 + e1);
        out[b * 24 + 2 * t]     = e0 * inv;
        out[b * 24 + 2 * t + 1] = e1 * inv;
    }
}

extern "C" void kernel_launch(void* const* d_in, const int* in_sizes, int n_in,
                              void* d_out, int out_size, void* d_ws, size_t ws_size,
                              hipStream_t stream) {
    const float* X    = (const float*)d_in[0];
    const int*   memb = (const int*)d_in[2];
    AdjPtrs adj;
    for (int d = 0; d < 10; ++d) adj.p[d] = (const int*)d_in[3 + d];
    const float* W1 = (const float*)d_in[13];
    const float* B1 = (const float*)d_in[14];
    const float* bg = (const float*)d_in[17];
    const float* bb = (const float*)d_in[18];
    const float* bm = (const float*)d_in[19];
    const float* bv = (const float*)d_in[20];
    const float* W2 = (const float*)d_in[31];
    const float* b2 = (const float*)d_in[32];
    float* out = (float*)d_out;

    k_pre<<<3565, 256, 0, stream>>>(W1, X);
    k_gc1<<<3129, 512, 0, stream>>>(B1, bg, bb, bm, bv, adj);
    k_seg<<<NSEG * NB, 128, 0, stream>>>(memb);
    k_final<<<NB, 256, 0, stream>>>(W2, b2, out);
}

// Round 9
// 185.858 us; speedup vs baseline: 1.0205x; 1.0205x over previous
//
#include <hip/hip_runtime.h>
#include <hip/hip_bf16.h>
#include <float.h>

#define NF 75
#define HID 128
#define NB 50
#define NT 12
#define BN_EPS 1e-3f
#define NSEG 64
#define ROWB 640   // LDS A-tile row stride in bytes (XOR-swizzled; 64*640 = 40960B -> 4 blocks/CU)

typedef __attribute__((ext_vector_type(8))) short short8;
typedef __attribute__((ext_vector_type(4))) float f32x4;

// Static device scratch. Fully written before read on every launch.
__device__ float g_bn1[(size_t)200000 * HID];            // 102.4 MB
__device__ float g_xp[(size_t)200000 * 80];              // padded X, 64 MB
__device__ float g_part[NSEG * NB * 256];                // segment partials
__device__ unsigned short g_wfrag[11 * 5 * 8 * 64 * 16]; // frag-ordered W, hi/lo bf16

struct AdjPtrs { const int* p[10]; };

__device__ __forceinline__ unsigned short f2bf(float x) {
    union { float f; unsigned u; } a; a.f = x;
    unsigned r = a.u + 0x7fffu + ((a.u >> 16) & 1u);   // RTNE
    return (unsigned short)(r >> 16);
}
__device__ __forceinline__ float bf2f(unsigned short h) {
    union { unsigned u; float f; } a; a.u = ((unsigned)h) << 16; return a.f;
}
__device__ __forceinline__ float fast_tanh(float x) {
    float e = __expf(2.f * x);
    return 1.f - 2.f / (e + 1.f);
}

__device__ constexpr int DS_[12] = {0,1000,20000,60000,120000,170000,185000,193000,197000,199000,199700,200000};

// ---------------- K_pre: merged W-conversion (blocks 0..439) + X-pad (blocks 440..3564) ----------------
__global__ __launch_bounds__(256) void k_pre(const float* __restrict__ W, const float* __restrict__ X) {
    if (blockIdx.x < 440) {
        if (threadIdx.x >= 64) return;
        const int id = blockIdx.x;                 // deg*40 + kt*8 + nt
        const int deg = id / 40, kt = (id / 8) % 5, nt = id % 8;
        const int lane = threadIdx.x;
        const int c  = nt * 16 + (lane & 15);
        const int kb = kt * 32 + (lane >> 4) * 8;
        unsigned short hs[8], ls[8];
#pragma unroll
        for (int i = 0; i < 8; ++i) {
            const int k = kb + i;
            float v = 0.f;
            if (deg > 0) {
                if (k < 75)                  v = W[(size_t)(2 * (deg - 1)) * NF * HID + (size_t)k * HID + c];
                else if (k >= 80 && k < 155) v = W[(size_t)(2 * (deg - 1) + 1) * NF * HID + (size_t)(k - 80) * HID + c];
            } else {
                if (k >= 80 && k < 155)      v = W[(size_t)20 * NF * HID + (size_t)(k - 80) * HID + c];
            }
            const unsigned short h = f2bf(v);
            hs[i] = h;
            ls[i] = f2bf(v - bf2f(h));
        }
        unsigned short* dst = g_wfrag + ((size_t)id * 64 + lane) * 16;
#pragma unroll
        for (int i = 0; i < 8; ++i) { dst[i] = hs[i]; dst[8 + i] = ls[i]; }
    } else {
        const int blk = blockIdx.x - 440;
        __shared__ float T[64 * 75];
        const f32x4* src = (const f32x4*)(X + (size_t)blk * 4800);
        for (int i = threadIdx.x; i < 1200; i += 256)
            *(f32x4*)&T[i * 4] = src[i];
        __syncthreads();
        f32x4* dst = (f32x4*)(g_xp + (size_t)blk * 5120);
        for (int o = threadIdx.x; o < 1280; o += 256) {
            const int row = o / 20, f0 = (o % 20) * 4;
            f32x4 r;
            r.x = (f0 + 0 < 75) ? T[row * 75 + f0 + 0] : 0.f;
            r.y = (f0 + 1 < 75) ? T[row * 75 + f0 + 1] : 0.f;
            r.z = (f0 + 2 < 75) ? T[row * 75 + f0 + 2] : 0.f;
            r.w = (f0 + 3 < 75) ? T[row * 75 + f0 + 3] : 0.f;
            dst[o] = r;
        }
    }
}

// ---------------- K1: gc1 via MFMA, one-shot staged A-tile, XOR-swizzled LDS ----------------
// 512 threads = 8 waves. Staging: thread (lane,wid) fills chunk k0=j*32+wid*4 of row=lane.
// Row layout (ROWB=640B): byte p = kt*128 + g*32 + hi/lo-bit4 + 8B-half; stored at p ^ ((row&7)<<4).
// MFMA: wave wid owns cols [wid*16,wid*16+16); A row=(l&15)+16m, k=(l>>4)*8+i.
template<int DEG>
__device__ __forceinline__ void gc1_body(
    int tile, char* __restrict__ A,
    const float* __restrict__ B,
    const float* __restrict__ bg, const float* __restrict__ bb,
    const float* __restrict__ bm, const float* __restrict__ bv,
    const int* __restrict__ adjBase)
{
    const int dStart = DS_[DEG], dEnd = DS_[DEG + 1];
    const int atom0  = dStart + tile * 64;
    const int nA     = min(64, dEnd - atom0);
    const int tid    = threadIdx.x;
    const int lane   = tid & 63;
    const int wid    = tid >> 6;

    constexpr int NR = (DEG > 0) ? DEG : 1;
    int adjr[NR];
    if (DEG > 0) {
        const int arow = (lane < nA) ? (atom0 + lane - dStart) : 0;
#pragma unroll
        for (int n = 0; n < DEG; ++n)
            adjr[n] = adjBase[(size_t)arow * DEG + n];
    }

    // swizzled staging pointers (hi and lo differ by XOR 16 after swizzle)
    const int sw    = (lane & 7) << 4;
    const int bhi   = (((wid >> 1) * 32) + ((wid & 1) * 8)) ^ sw;
    char* whi = A + lane * ROWB + bhi;
    char* wlo = A + lane * ROWB + (bhi ^ 16);

    auto issue = [&](int jj, f32x4* t) {
        const int k0 = jj * 32 + wid * 4;          // wave-uniform branch selector
        if (k0 < 80) {
            if (DEG > 0) {
#pragma unroll
                for (int n = 0; n < DEG; ++n)
                    t[n] = *(const f32x4*)(g_xp + (size_t)adjr[n] * 80 + k0);
            } else {
                t[0] = (f32x4){0.f, 0.f, 0.f, 0.f};
            }
        } else {
            if (lane < nA)
                t[0] = *(const f32x4*)(g_xp + (size_t)(atom0 + lane) * 80 + (k0 - 80));
            else
                t[0] = (f32x4){0.f, 0.f, 0.f, 0.f};
        }
    };
    auto finish = [&](int jj, f32x4* t) {
        const int k0 = jj * 32 + wid * 4;
        f32x4 v = t[0];
        if (k0 < 80 && DEG > 1) {
#pragma unroll
            for (int n = 1; n < DEG; ++n) v += t[n];
        }
        if (k0 < 80 && DEG > 0 && lane >= nA) v = (f32x4){0.f, 0.f, 0.f, 0.f};
        unsigned long long hp = 0, lp = 0;
#pragma unroll
        for (int ii = 0; ii < 4; ++ii) {
            const unsigned short h = f2bf(v[ii]);
            const unsigned short l = f2bf(v[ii] - bf2f(h));
            hp |= (unsigned long long)h << (16 * ii);
            lp |= (unsigned long long)l << (16 * ii);
        }
        *(unsigned long long*)(whi + jj * 128) = hp;
        *(unsigned long long*)(wlo + jj * 128) = lp;
    };

    if constexpr (DEG <= 4) {
        // depth-2 software pipeline, fully unrolled (static reg indexing)
        f32x4 tA[NR], tB[NR];
        issue(0, tA);
#pragma unroll
        for (int j = 0; j < 5; ++j) {
            f32x4* cur = (j & 1) ? tB : tA;
            f32x4* nxt = (j & 1) ? tA : tB;
            if (j < 4) issue(j + 1, nxt);
            finish(j, cur);
        }
    } else {
#pragma unroll 1
        for (int j = 0; j < 5; ++j) {
            f32x4 t[NR];
            issue(j, t);
            finish(j, t);
        }
    }
    __syncthreads();

    f32x4 acc[4] = {};
    const int gk = lane >> 4;
    const int roff_hi = (gk * 32) ^ ((lane & 7) << 4);   // row&7 == lane&7 (rows differ by m*16)
    const int roff_lo = roff_hi ^ 16;
    const int kt0 = (DEG == 0) ? 2 : 0;
#pragma unroll
    for (int kt = kt0; kt < 5; ++kt) {
        const unsigned short* wp = g_wfrag + ((size_t)(((DEG * 5 + kt) * 8 + wid) * 64 + lane)) * 16;
        const short8 wh = *(const short8*)wp;
        const short8 wl = *(const short8*)(wp + 8);
#pragma unroll
        for (int m = 0; m < 4; ++m) {
            const char* rb = A + (m * 16 + (lane & 15)) * ROWB + kt * 128;
            const short8 ah = *(const short8*)(rb + roff_hi);
            const short8 al = *(const short8*)(rb + roff_lo);
            acc[m] = __builtin_amdgcn_mfma_f32_16x16x32_bf16(ah, wh, acc[m], 0, 0, 0);
            acc[m] = __builtin_amdgcn_mfma_f32_16x16x32_bf16(al, wh, acc[m], 0, 0, 0);
            acc[m] = __builtin_amdgcn_mfma_f32_16x16x32_bf16(ah, wl, acc[m], 0, 0, 0);
        }
    }

    const int col = wid * 16 + (lane & 15);
    const float bsum = (DEG > 0)
        ? (B[(size_t)(2 * (DEG - 1)) * HID + col] + B[(size_t)(2 * (DEG - 1) + 1) * HID + col])
        : B[(size_t)20 * HID + col];
    const float s  = bg[col] * rsqrtf(bv[col] + BN_EPS);
    const float sh = bb[col] - bm[col] * s;
#pragma unroll
    for (int m = 0; m < 4; ++m) {
#pragma unroll
        for (int j = 0; j < 4; ++j) {
            const int r = m * 16 + (lane >> 4) * 4 + j;
            if (r < nA)
                g_bn1[(size_t)(atom0 + r) * HID + col] = fast_tanh(acc[m][j] + bsum) * s + sh;
        }
    }
}

__global__ __launch_bounds__(512, 8) void k_gc1(
    const float* __restrict__ B,
    const float* __restrict__ bg, const float* __restrict__ bb,
    const float* __restrict__ bm, const float* __restrict__ bv,
    AdjPtrs adj)
{
    // heavy-first: deg 10,9,...,1,0
    constexpr int TSH[12]    = {0,5,16,48,111,236,471,1253,2191,2816,3113,3129};
    constexpr int DEGORD[11] = {10,9,8,7,6,5,4,3,2,1,0};
    __shared__ __align__(16) char A[64 * ROWB];   // 40960 B -> 4 blocks/CU (160 KiB exactly)

    const int blk = blockIdx.x;
    int seg = 0;
#pragma unroll
    for (int s = 1; s <= 10; ++s) if (blk >= TSH[s]) seg = s;
    const int deg  = DEGORD[seg];
    const int tile = blk - TSH[seg];

    switch (deg) {
        case 0:  gc1_body<0 >(tile, A, B, bg, bb, bm, bv, nullptr);   break;
        case 1:  gc1_body<1 >(tile, A, B, bg, bb, bm, bv, adj.p[0]);  break;
        case 2:  gc1_body<2 >(tile, A, B, bg, bb, bm, bv, adj.p[1]);  break;
        case 3:  gc1_body<3 >(tile, A, B, bg, bb, bm, bv, adj.p[2]);  break;
        case 4:  gc1_body<4 >(tile, A, B, bg, bb, bm, bv, adj.p[3]);  break;
        case 5:  gc1_body<5 >(tile, A, B, bg, bb, bm, bv, adj.p[4]);  break;
        case 6:  gc1_body<6 >(tile, A, B, bg, bb, bm, bv, adj.p[5]);  break;
        case 7:  gc1_body<7 >(tile, A, B, bg, bb, bm, bv, adj.p[6]);  break;
        case 8:  gc1_body<8 >(tile, A, B, bg, bb, bm, bv, adj.p[7]);  break;
        case 9:  gc1_body<9 >(tile, A, B, bg, bb, bm, bv, adj.p[8]);  break;
        case 10: gc1_body<10>(tile, A, B, bg, bb, bm, bv, adj.p[9]);  break;
    }
}

// ---------------- K2: deterministic segment sum/max partials ----------------
__global__ __launch_bounds__(128) void k_seg(const int* __restrict__ memb)
{
    const int b = blockIdx.x % NB;
    const int s = blockIdx.x / NB;
    const int aLo = s * (200000 / NSEG);
    const int aHi = aLo + (200000 / NSEG);
    const int wave = threadIdx.x >> 6;
    const int lane = threadIdx.x & 63;

    __shared__ int q[2][256];
    __shared__ int qn[2];
    int* myq = q[wave];
    int nq = 0;

    for (int base = aLo + wave * 64; base < aHi; base += 128) {
        const int a = base + lane;
        const bool m = (a < aHi) && (memb[a] == b);
        const unsigned long long bal = __ballot(m);
        if (m) {
            const int pos = __popcll(bal & ((1ull << lane) - 1ull));
            if (nq + pos < 256) myq[nq + pos] = a;
        }
        nq += __popcll(bal);
    }
    if (lane == 0) qn[wave] = min(nq, 256);
    __syncthreads();

    const int c = threadIdx.x;  // col 0..127
    float sum = 0.f, mx = -FLT_MAX;
#pragma unroll
    for (int w2 = 0; w2 < 2; ++w2) {
        const int n = qn[w2];
        for (int i = 0; i < n; ++i) {
            const float v = g_bn1[(size_t)q[w2][i] * HID + c];
            sum += v;
            mx = fmaxf(mx, v);
        }
    }
    float* pd = g_part + (size_t)(s * NB + b) * 256;
    pd[c] = sum;
    pd[128 + c] = mx;
}

// ---------------- K3: reduce partials, tanh, dense [256,24], softmax pairs ----------------
__global__ __launch_bounds__(256) void k_final(const float* __restrict__ W2,
                                               const float* __restrict__ b2,
                                               float* __restrict__ out)
{
    const int b = blockIdx.x;
    const int t = threadIdx.x;
    __shared__ float ro[256];
    __shared__ float lg[24];

    {
        float v;
        if (t < 128) {
            float sv = 0.f;
            for (int s = 0; s < NSEG; ++s) sv += g_part[(size_t)(s * NB + b) * 256 + t];
            v = sv;
        } else {
            float mv = -FLT_MAX;
            for (int s = 0; s < NSEG; ++s) mv = fmaxf(mv, g_part[(size_t)(s * NB + b) * 256 + t]);
            v = mv;
        }
        ro[t] = tanhf(v);
    }
    __syncthreads();
    if (t < 24) {
        float acc = b2[t];
        for (int c = 0; c < 256; ++c) acc = fmaf(ro[c], W2[c * 24 + t], acc);
        lg[t] = acc;
    }
    __syncthreads();
    if (t < NT) {
        const float l0 = lg[2 * t], l1 = lg[2 * t + 1];
        const float m = fmaxf(l0, l1);
        const float e0 = expf(l0 - m), e1 = expf(l1 - m);
        const float inv = 1.f / (e0 + e1);
        out[b * 24 + 2 * t]     = e0 * inv;
        out[b * 24 + 2 * t + 1] = e1 * inv;
    }
}

extern "C" void kernel_launch(void* const* d_in, const int* in_sizes, int n_in,
                              void* d_out, int out_size, void* d_ws, size_t ws_size,
                              hipStream_t stream) {
    const float* X    = (const float*)d_in[0];
    const int*   memb = (const int*)d_in[2];
    AdjPtrs adj;
    for (int d = 0; d < 10; ++d) adj.p[d] = (const int*)d_in[3 + d];
    const float* W1 = (const float*)d_in[13];
    const float* B1 = (const float*)d_in[14];
    const float* bg = (const float*)d_in[17];
    const float* bb = (const float*)d_in[18];
    const float* bm = (const float*)d_in[19];
    const float* bv = (const float*)d_in[20];
    const float* W2 = (const float*)d_in[31];
    const float* b2 = (const float*)d_in[32];
    float* out = (float*)d_out;

    k_pre<<<3565, 256, 0, stream>>>(W1, X);
    k_gc1<<<3129, 512, 0, stream>>>(B1, bg, bb, bm, bv, adj);
    k_seg<<<NSEG * NB, 128, 0, stream>>>(memb);
    k_final<<<NB, 256, 0, stream>>>(W2, b2, out);
}

// Round 10
// 170.231 us; speedup vs baseline: 1.1142x; 1.0918x over previous
//
#include <hip/hip_runtime.h>
#include <hip/hip_bf16.h>
#include <float.h>

#define NF 75
#define HID 128
#define NB 50
#define NT 12
#define BN_EPS 1e-3f
#define NSEG 128
#define SLEN 1563   // ceil(200000/128); last stripe short
#define ROWB 656    // LDS A-tile row stride in bytes (164 dwords = 4 mod 32 -> bank rotation)

typedef __attribute__((ext_vector_type(8))) short short8;
typedef __attribute__((ext_vector_type(4))) float f32x4;

// Static device scratch. Fully written before read on every launch.
__device__ float g_bn1[(size_t)200000 * HID];            // 102.4 MB
__device__ float g_xp[(size_t)200000 * 80];              // padded X, 64 MB
__device__ float g_part[NSEG * NB * 256];                // segment partials (6.5 MB)
__device__ unsigned short g_wfrag[11 * 5 * 8 * 64 * 16]; // frag-ordered W, hi/lo bf16
__device__ unsigned char g_memb8[200000];                // membership as u8

struct AdjPtrs { const int* p[10]; };

__device__ __forceinline__ unsigned short f2bf(float x) {
    union { float f; unsigned u; } a; a.f = x;
    unsigned r = a.u + 0x7fffu + ((a.u >> 16) & 1u);   // RTNE
    return (unsigned short)(r >> 16);
}
__device__ __forceinline__ float bf2f(unsigned short h) {
    union { unsigned u; float f; } a; a.u = ((unsigned)h) << 16; return a.f;
}
__device__ __forceinline__ float fast_tanh(float x) {
    float e = __expf(2.f * x);
    return 1.f - 2.f / (e + 1.f);
}

__device__ constexpr int DS_[12] = {0,1000,20000,60000,120000,170000,185000,193000,197000,199000,199700,200000};

// ---------------- K_pre: W-conv (0..439) + X-pad (440..3564) + memb->u8 (3565..3760) ----------------
__global__ __launch_bounds__(256) void k_pre(const float* __restrict__ W, const float* __restrict__ X,
                                             const int* __restrict__ memb) {
    if (blockIdx.x < 440) {
        if (threadIdx.x >= 64) return;
        const int id = blockIdx.x;                 // deg*40 + kt*8 + nt
        const int deg = id / 40, kt = (id / 8) % 5, nt = id % 8;
        const int lane = threadIdx.x;
        const int c  = nt * 16 + (lane & 15);
        const int kb = kt * 32 + (lane >> 4) * 8;
        unsigned short hs[8], ls[8];
#pragma unroll
        for (int i = 0; i < 8; ++i) {
            const int k = kb + i;
            float v = 0.f;
            if (deg > 0) {
                if (k < 75)                  v = W[(size_t)(2 * (deg - 1)) * NF * HID + (size_t)k * HID + c];
                else if (k >= 80 && k < 155) v = W[(size_t)(2 * (deg - 1) + 1) * NF * HID + (size_t)(k - 80) * HID + c];
            } else {
                if (k >= 80 && k < 155)      v = W[(size_t)20 * NF * HID + (size_t)(k - 80) * HID + c];
            }
            const unsigned short h = f2bf(v);
            hs[i] = h;
            ls[i] = f2bf(v - bf2f(h));
        }
        unsigned short* dst = g_wfrag + ((size_t)id * 64 + lane) * 16;
#pragma unroll
        for (int i = 0; i < 8; ++i) { dst[i] = hs[i]; dst[8 + i] = ls[i]; }
    } else if (blockIdx.x < 3565) {
        const int blk = blockIdx.x - 440;
        __shared__ float T[64 * 75];
        const f32x4* src = (const f32x4*)(X + (size_t)blk * 4800);
        for (int i = threadIdx.x; i < 1200; i += 256)
            *(f32x4*)&T[i * 4] = src[i];
        __syncthreads();
        f32x4* dst = (f32x4*)(g_xp + (size_t)blk * 5120);
        for (int o = threadIdx.x; o < 1280; o += 256) {
            const int row = o / 20, f0 = (o % 20) * 4;
            f32x4 r;
            r.x = (f0 + 0 < 75) ? T[row * 75 + f0 + 0] : 0.f;
            r.y = (f0 + 1 < 75) ? T[row * 75 + f0 + 1] : 0.f;
            r.z = (f0 + 2 < 75) ? T[row * 75 + f0 + 2] : 0.f;
            r.w = (f0 + 3 < 75) ? T[row * 75 + f0 + 3] : 0.f;
            dst[o] = r;
        }
    } else {
        const int base = (blockIdx.x - 3565) * 1024 + threadIdx.x * 4;
#pragma unroll
        for (int i = 0; i < 4; ++i) {
            const int a = base + i;
            if (a < 200000) g_memb8[a] = (unsigned char)memb[a];
        }
    }
}

// ---------------- K1: gc1 via MFMA, one-shot staged A-tile (R6-proven layout) ----------------
// 512 threads = 8 waves. Staging: thread (lane,wid) fills chunk k0=j*32+wid*4 of row=lane.
// Row layout (ROWB=656B): kt*128 + g*32 + {hi 16B | lo 16B}; stride rotates banks 4/row.
// MFMA: wave wid owns cols [wid*16,wid*16+16); A row=(l&15)+16m, k=(l>>4)*8+i.
template<int DEG>
__device__ __forceinline__ void gc1_body(
    int tile, char* __restrict__ A,
    const float* __restrict__ B,
    const float* __restrict__ bg, const float* __restrict__ bb,
    const float* __restrict__ bm, const float* __restrict__ bv,
    const int* __restrict__ adjBase)
{
    const int dStart = DS_[DEG], dEnd = DS_[DEG + 1];
    const int atom0  = dStart + tile * 64;
    const int nA     = min(64, dEnd - atom0);
    const int tid    = threadIdx.x;
    const int lane   = tid & 63;
    const int wid    = tid >> 6;

    constexpr int NR = (DEG > 0) ? DEG : 1;
    int adjr[NR];
    if (DEG > 0) {
        const int arow = (lane < nA) ? (atom0 + lane - dStart) : 0;
#pragma unroll
        for (int n = 0; n < DEG; ++n)
            adjr[n] = adjBase[(size_t)arow * DEG + n];
    }

    char* wbase = A + lane * ROWB + (wid >> 1) * 32 + (wid & 1) * 8;

    auto issue = [&](int jj, f32x4* t) {
        const int k0 = jj * 32 + wid * 4;          // wave-uniform branch selector
        if (k0 < 80) {
            if (DEG > 0) {
#pragma unroll
                for (int n = 0; n < DEG; ++n)
                    t[n] = *(const f32x4*)(g_xp + (size_t)adjr[n] * 80 + k0);
            } else {
                t[0] = (f32x4){0.f, 0.f, 0.f, 0.f};
            }
        } else {
            if (lane < nA)
                t[0] = *(const f32x4*)(g_xp + (size_t)(atom0 + lane) * 80 + (k0 - 80));
            else
                t[0] = (f32x4){0.f, 0.f, 0.f, 0.f};
        }
    };
    auto finish = [&](int jj, f32x4* t) {
        const int k0 = jj * 32 + wid * 4;
        f32x4 v = t[0];
        if (k0 < 80 && DEG > 1) {
#pragma unroll
            for (int n = 1; n < DEG; ++n) v += t[n];
        }
        if (k0 < 80 && DEG > 0 && lane >= nA) v = (f32x4){0.f, 0.f, 0.f, 0.f};
        unsigned long long hp = 0, lp = 0;
#pragma unroll
        for (int ii = 0; ii < 4; ++ii) {
            const unsigned short h = f2bf(v[ii]);
            const unsigned short l = f2bf(v[ii] - bf2f(h));
            hp |= (unsigned long long)h << (16 * ii);
            lp |= (unsigned long long)l << (16 * ii);
        }
        *(unsigned long long*)(wbase + jj * 128)      = hp;
        *(unsigned long long*)(wbase + jj * 128 + 16) = lp;
    };

    if constexpr (DEG <= 4) {
        // depth-2 software pipeline, fully unrolled (static reg indexing)
        f32x4 tA[NR], tB[NR];
        issue(0, tA);
#pragma unroll
        for (int j = 0; j < 5; ++j) {
            f32x4* cur = (j & 1) ? tB : tA;
            f32x4* nxt = (j & 1) ? tA : tB;
            if (j < 4) issue(j + 1, nxt);
            finish(j, cur);
        }
    } else {
#pragma unroll 1
        for (int j = 0; j < 5; ++j) {
            f32x4 t[NR];
            issue(j, t);
            finish(j, t);
        }
    }
    __syncthreads();

    f32x4 acc[4] = {};
    const int gk = lane >> 4;
    const int kt0 = (DEG == 0) ? 2 : 0;
#pragma unroll
    for (int kt = kt0; kt < 5; ++kt) {
        const unsigned short* wp = g_wfrag + ((size_t)(((DEG * 5 + kt) * 8 + wid) * 64 + lane)) * 16;
        const short8 wh = *(const short8*)wp;
        const short8 wl = *(const short8*)(wp + 8);
#pragma unroll
        for (int m = 0; m < 4; ++m) {
            const char* ab = A + (m * 16 + (lane & 15)) * ROWB + kt * 128 + gk * 32;
            const short8 ah = *(const short8*)ab;
            const short8 al = *(const short8*)(ab + 16);
            acc[m] = __builtin_amdgcn_mfma_f32_16x16x32_bf16(ah, wh, acc[m], 0, 0, 0);
            acc[m] = __builtin_amdgcn_mfma_f32_16x16x32_bf16(al, wh, acc[m], 0, 0, 0);
            acc[m] = __builtin_amdgcn_mfma_f32_16x16x32_bf16(ah, wl, acc[m], 0, 0, 0);
        }
    }

    const int col = wid * 16 + (lane & 15);
    const float bsum = (DEG > 0)
        ? (B[(size_t)(2 * (DEG - 1)) * HID + col] + B[(size_t)(2 * (DEG - 1) + 1) * HID + col])
        : B[(size_t)20 * HID + col];
    const float s  = bg[col] * rsqrtf(bv[col] + BN_EPS);
    const float sh = bb[col] - bm[col] * s;
#pragma unroll
    for (int m = 0; m < 4; ++m) {
#pragma unroll
        for (int j = 0; j < 4; ++j) {
            const int r = m * 16 + (lane >> 4) * 4 + j;
            if (r < nA)
                g_bn1[(size_t)(atom0 + r) * HID + col] = fast_tanh(acc[m][j] + bsum) * s + sh;
        }
    }
}

__global__ __launch_bounds__(512, 6) void k_gc1(
    const float* __restrict__ B,
    const float* __restrict__ bg, const float* __restrict__ bb,
    const float* __restrict__ bm, const float* __restrict__ bv,
    AdjPtrs adj)
{
    // heavy-first: deg 10,9,...,1,0
    constexpr int TSH[12]    = {0,5,16,48,111,236,471,1253,2191,2816,3113,3129};
    constexpr int DEGORD[11] = {10,9,8,7,6,5,4,3,2,1,0};
    __shared__ __align__(16) char A[64 * ROWB];   // 41984 B -> 3 blocks/CU

    const int blk = blockIdx.x;
    int seg = 0;
#pragma unroll
    for (int s = 1; s <= 10; ++s) if (blk >= TSH[s]) seg = s;
    const int deg  = DEGORD[seg];
    const int tile = blk - TSH[seg];

    switch (deg) {
        case 0:  gc1_body<0 >(tile, A, B, bg, bb, bm, bv, nullptr);   break;
        case 1:  gc1_body<1 >(tile, A, B, bg, bb, bm, bv, adj.p[0]);  break;
        case 2:  gc1_body<2 >(tile, A, B, bg, bb, bm, bv, adj.p[1]);  break;
        case 3:  gc1_body<3 >(tile, A, B, bg, bb, bm, bv, adj.p[2]);  break;
        case 4:  gc1_body<4 >(tile, A, B, bg, bb, bm, bv, adj.p[3]);  break;
        case 5:  gc1_body<5 >(tile, A, B, bg, bb, bm, bv, adj.p[4]);  break;
        case 6:  gc1_body<6 >(tile, A, B, bg, bb, bm, bv, adj.p[5]);  break;
        case 7:  gc1_body<7 >(tile, A, B, bg, bb, bm, bv, adj.p[6]);  break;
        case 8:  gc1_body<8 >(tile, A, B, bg, bb, bm, bv, adj.p[7]);  break;
        case 9:  gc1_body<9 >(tile, A, B, bg, bb, bm, bv, adj.p[8]);  break;
        case 10: gc1_body<10>(tile, A, B, bg, bb, bm, bv, adj.p[9]);  break;
    }
}

// ---------------- K2: deterministic segment sum/max partials (u8 membership) ----------------
__global__ __launch_bounds__(128) void k_seg()
{
    const int b = blockIdx.x % NB;
    const int s = blockIdx.x / NB;
    const int aLo = s * SLEN;
    const int aHi = min(aLo + SLEN, 200000);
    const int wave = threadIdx.x >> 6;
    const int lane = threadIdx.x & 63;

    __shared__ int q[2][256];
    __shared__ int qn[2];
    int* myq = q[wave];
    int nq = 0;

    for (int base = aLo + wave * 64; base < aHi; base += 128) {
        const int a = base + lane;
        const bool m = (a < aHi) && (g_memb8[a] == (unsigned char)b);
        const unsigned long long bal = __ballot(m);
        if (m) {
            const int pos = __popcll(bal & ((1ull << lane) - 1ull));
            if (nq + pos < 256) myq[nq + pos] = a;
        }
        nq += __popcll(bal);
    }
    if (lane == 0) qn[wave] = min(nq, 256);
    __syncthreads();

    const int c = threadIdx.x;  // col 0..127
    float sum = 0.f, mx = -FLT_MAX;
#pragma unroll
    for (int w2 = 0; w2 < 2; ++w2) {
        const int n = qn[w2];
        for (int i = 0; i < n; ++i) {
            const float v = g_bn1[(size_t)q[w2][i] * HID + c];
            sum += v;
            mx = fmaxf(mx, v);
        }
    }
    float* pd = g_part + (size_t)(s * NB + b) * 256;
    pd[c] = sum;
    pd[128 + c] = mx;
}

// ---------------- K3: reduce partials (4-way chunked), tanh, dense, softmax ----------------
__global__ __launch_bounds__(1024) void k_final(const float* __restrict__ W2,
                                                const float* __restrict__ b2,
                                                float* __restrict__ out)
{
    const int b  = blockIdx.x;
    const int t  = threadIdx.x;
    const int c  = t & 255;
    const int cc = t >> 8;           // 0..3, each reduces 32 stripes
    __shared__ float red[4][256];
    __shared__ float ro[256];
    __shared__ float lg[24];

    {
        float v;
        if (c < 128) {
            float sv = 0.f;
            for (int s = cc * 32; s < cc * 32 + 32; ++s)
                sv += g_part[(size_t)(s * NB + b) * 256 + c];
            v = sv;
        } else {
            float mv = -FLT_MAX;
            for (int s = cc * 32; s < cc * 32 + 32; ++s)
                mv = fmaxf(mv, g_part[(size_t)(s * NB + b) * 256 + c]);
            v = mv;
        }
        red[cc][c] = v;
    }
    __syncthreads();
    if (cc == 0) {
        float v;
        if (c < 128) v = red[0][c] + red[1][c] + red[2][c] + red[3][c];
        else         v = fmaxf(fmaxf(red[0][c], red[1][c]), fmaxf(red[2][c], red[3][c]));
        ro[c] = tanhf(v);
    }
    __syncthreads();
    if (t < 24) {
        float acc = b2[t];
        for (int cx = 0; cx < 256; ++cx) acc = fmaf(ro[cx], W2[cx * 24 + t], acc);
        lg[t] = acc;
    }
    __syncthreads();
    if (t < NT) {
        const float l0 = lg[2 * t], l1 = lg[2 * t + 1];
        const float m = fmaxf(l0, l1);
        const float e0 = expf(l0 - m), e1 = expf(l1 - m);
        const float inv = 1.f / (e0 + e1);
        out[b * 24 + 2 * t]     = e0 * inv;
        out[b * 24 + 2 * t + 1] = e1 * inv;
    }
}

extern "C" void kernel_launch(void* const* d_in, const int* in_sizes, int n_in,
                              void* d_out, int out_size, void* d_ws, size_t ws_size,
                              hipStream_t stream) {
    const float* X    = (const float*)d_in[0];
    const int*   memb = (const int*)d_in[2];
    AdjPtrs adj;
    for (int d = 0; d < 10; ++d) adj.p[d] = (const int*)d_in[3 + d];
    const float* W1 = (const float*)d_in[13];
    const float* B1 = (const float*)d_in[14];
    const float* bg = (const float*)d_in[17];
    const float* bb = (const float*)d_in[18];
    const float* bm = (const float*)d_in[19];
    const float* bv = (const float*)d_in[20];
    const float* W2 = (const float*)d_in[31];
    const float* b2 = (const float*)d_in[32];
    float* out = (float*)d_out;

    k_pre<<<3761, 256, 0, stream>>>(W1, X, memb);
    k_gc1<<<3129, 512, 0, stream>>>(B1, bg, bb, bm, bv, adj);
    k_seg<<<NSEG * NB, 128, 0, stream>>>();
    k_final<<<NB, 1024, 0, stream>>>(W2, b2, out);
}

// Round 11
// 126.927 us; speedup vs baseline: 1.4943x; 1.3412x over previous
//
#include <hip/hip_runtime.h>
#include <hip/hip_bf16.h>
#include <float.h>

#define NF 75
#define HID 128
#define NB 50
#define NT 12
#define BN_EPS 1e-3f
#define NSEG 128
#define SLEN 1563   // ceil(200000/128)
#define ROWB 656    // LDS A-tile row stride in bytes (164 dwords = 4 mod 32 -> bank rotation)

typedef __attribute__((ext_vector_type(8))) short short8;
typedef __attribute__((ext_vector_type(4))) float f32x4;
typedef __attribute__((ext_vector_type(4))) unsigned int u32x4;

// Static device scratch. Fully written before read on every launch.
__device__ unsigned short g_xb[(size_t)200000 * 80];     // padded X, bf16, 32 MB
__device__ unsigned short g_bn1b[(size_t)200000 * 128];  // bn1, bf16, 51.2 MB
__device__ float g_part[NSEG * NB * 256];                // segment partials (6.5 MB)
__device__ unsigned short g_wfrag[11 * 5 * 8 * 64 * 16]; // frag-ordered W, hi/lo bf16
__device__ unsigned char g_memb8[200000];                // membership as u8

struct AdjPtrs { const int* p[10]; };

__device__ __forceinline__ unsigned short f2bf(float x) {
    union { float f; unsigned u; } a; a.f = x;
    unsigned r = a.u + 0x7fffu + ((a.u >> 16) & 1u);   // RTNE
    return (unsigned short)(r >> 16);
}
__device__ __forceinline__ float bf2f(unsigned short h) {
    union { unsigned u; float f; } a; a.u = ((unsigned)h) << 16; return a.f;
}
__device__ __forceinline__ float fast_tanh(float x) {
    float e = __expf(2.f * x);
    return 1.f - 2.f / (e + 1.f);
}

__device__ constexpr int DS_[12] = {0,1000,20000,60000,120000,170000,185000,193000,197000,199000,199700,200000};

// ---------------- K_pre: W-conv (0..439) + X->bf16 pad (440..3564) + memb->u8 (3565..3760) ----------------
__global__ __launch_bounds__(256) void k_pre(const float* __restrict__ W, const float* __restrict__ X,
                                             const int* __restrict__ memb) {
    if (blockIdx.x < 440) {
        if (threadIdx.x >= 64) return;
        const int id = blockIdx.x;                 // deg*40 + kt*8 + nt
        const int deg = id / 40, kt = (id / 8) % 5, nt = id % 8;
        const int lane = threadIdx.x;
        const int c  = nt * 16 + (lane & 15);
        const int kb = kt * 32 + (lane >> 4) * 8;
        unsigned short hs[8], ls[8];
#pragma unroll
        for (int i = 0; i < 8; ++i) {
            const int k = kb + i;
            float v = 0.f;
            if (deg > 0) {
                if (k < 75)                  v = W[(size_t)(2 * (deg - 1)) * NF * HID + (size_t)k * HID + c];
                else if (k >= 80 && k < 155) v = W[(size_t)(2 * (deg - 1) + 1) * NF * HID + (size_t)(k - 80) * HID + c];
            } else {
                if (k >= 80 && k < 155)      v = W[(size_t)20 * NF * HID + (size_t)(k - 80) * HID + c];
            }
            const unsigned short h = f2bf(v);
            hs[i] = h;
            ls[i] = f2bf(v - bf2f(h));
        }
        unsigned short* dst = g_wfrag + ((size_t)id * 64 + lane) * 16;
#pragma unroll
        for (int i = 0; i < 8; ++i) { dst[i] = hs[i]; dst[8 + i] = ls[i]; }
    } else if (blockIdx.x < 3565) {
        const int blk = blockIdx.x - 440;
        __shared__ float T[64 * 75];
        const f32x4* src = (const f32x4*)(X + (size_t)blk * 4800);
        for (int i = threadIdx.x; i < 1200; i += 256)
            *(f32x4*)&T[i * 4] = src[i];
        __syncthreads();
        u32x4* dst = (u32x4*)(g_xb + (size_t)blk * 5120);   // 64 rows x 80 bf16
        for (int o = threadIdx.x; o < 640; o += 256) {
            const int row = o / 10, c0 = (o % 10) * 8;
            u32x4 r;
#pragma unroll
            for (int i = 0; i < 4; ++i) {
                const int f0 = c0 + 2 * i, f1 = f0 + 1;
                const unsigned short h0 = (f0 < 75) ? f2bf(T[row * 75 + f0]) : (unsigned short)0;
                const unsigned short h1 = (f1 < 75) ? f2bf(T[row * 75 + f1]) : (unsigned short)0;
                r[i] = (unsigned)h0 | ((unsigned)h1 << 16);
            }
            dst[o] = r;
        }
    } else {
        const int base = (blockIdx.x - 3565) * 1024 + threadIdx.x * 4;
#pragma unroll
        for (int i = 0; i < 4; ++i) {
            const int a = base + i;
            if (a < 200000) g_memb8[a] = (unsigned char)memb[a];
        }
    }
}

// ---------------- K1: gc1 via MFMA, bf16 gather, one-shot staged A-tile ----------------
// 512 threads = 8 waves. Row = lane; wave wid handles slots {wid, wid+8, wid+16(<20)}.
// Slot s<10: rel chunk s (k-group s); s>=10: self chunk s-10 (k-group s).
// LDS row (ROWB=656): k-group G at G*32: {hi 16B | lo 16B}. MFMA frag G = kt*4 + (l>>4).
template<int DEG>
__device__ __forceinline__ void gc1_body(
    int tile, char* __restrict__ A,
    const float* __restrict__ B,
    const float* __restrict__ bg, const float* __restrict__ bb,
    const float* __restrict__ bm, const float* __restrict__ bv,
    const int* __restrict__ adjBase)
{
    const int dStart = DS_[DEG], dEnd = DS_[DEG + 1];
    const int atom0  = dStart + tile * 64;
    const int nA     = min(64, dEnd - atom0);
    const int tid    = threadIdx.x;
    const int lane   = tid & 63;
    const int wid    = tid >> 6;

    constexpr int NR = (DEG > 0) ? DEG : 1;
    int adjr[NR];
    if (DEG > 0) {
        const int arow = (lane < nA) ? (atom0 + lane - dStart) : 0;
#pragma unroll
        for (int n = 0; n < DEG; ++n)
            adjr[n] = adjBase[(size_t)arow * DEG + n];
    }

    char* const rowp = A + lane * ROWB;

    // issue a slot's loads (s wave-uniform)
    auto issue = [&](int s, u32x4* t) {
        if (s < 10) {
            if (DEG > 0) {
#pragma unroll
                for (int n = 0; n < DEG; ++n)
                    t[n] = *(const u32x4*)(g_xb + (size_t)adjr[n] * 80 + s * 8);
            } else {
                t[0] = (u32x4){0u, 0u, 0u, 0u};
            }
        } else {
            if (lane < nA)
                t[0] = *(const u32x4*)(g_xb + (size_t)(atom0 + lane) * 80 + (s - 10) * 8);
            else
                t[0] = (u32x4){0u, 0u, 0u, 0u};
        }
    };
    auto finish = [&](int s, u32x4* t) {
        u32x4 hp, lp;
        if (s < 10) {
            float v0[4] = {0.f, 0.f, 0.f, 0.f};
            float v1[4] = {0.f, 0.f, 0.f, 0.f};
            if (DEG > 0 && lane < nA) {
#pragma unroll
                for (int n = 0; n < DEG; ++n) {
#pragma unroll
                    for (int i = 0; i < 4; ++i) {
                        const unsigned u = t[n][i];
                        v0[i] += __uint_as_float(u << 16);
                        v1[i] += __uint_as_float(u & 0xFFFF0000u);
                    }
                }
            }
#pragma unroll
            for (int i = 0; i < 4; ++i) {
                const unsigned short h0 = f2bf(v0[i]), h1 = f2bf(v1[i]);
                const unsigned short l0 = f2bf(v0[i] - bf2f(h0)), l1 = f2bf(v1[i] - bf2f(h1));
                hp[i] = (unsigned)h0 | ((unsigned)h1 << 16);
                lp[i] = (unsigned)l0 | ((unsigned)l1 << 16);
            }
        } else {
            hp = t[0];                                 // self values are exact bf16: hi=raw, lo=0
            lp = (u32x4){0u, 0u, 0u, 0u};
        }
        *(u32x4*)(rowp + s * 32)      = hp;
        *(u32x4*)(rowp + s * 32 + 16) = lp;
    };

    const bool haveC = (wid < 4);                      // slot wid+16 (self chunk wid+6)
    if constexpr (DEG <= 4) {
        u32x4 tA[NR], tB[NR], tC;
        issue(wid, tA);
        issue(wid + 8, tB);
        finish(wid, tA);
        if (haveC) {
            tC = (lane < nA) ? *(const u32x4*)(g_xb + (size_t)(atom0 + lane) * 80 + (wid + 6) * 8)
                             : (u32x4){0u, 0u, 0u, 0u};
        }
        finish(wid + 8, tB);
        if (haveC) {
            *(u32x4*)(rowp + (wid + 16) * 32)      = tC;
            *(u32x4*)(rowp + (wid + 16) * 32 + 16) = (u32x4){0u, 0u, 0u, 0u};
        }
    } else {
        { u32x4 t[NR]; issue(wid, t); finish(wid, t); }
        { u32x4 t[NR]; issue(wid + 8, t); finish(wid + 8, t); }
        if (haveC) {
            u32x4 tC = (lane < nA) ? *(const u32x4*)(g_xb + (size_t)(atom0 + lane) * 80 + (wid + 6) * 8)
                                   : (u32x4){0u, 0u, 0u, 0u};
            *(u32x4*)(rowp + (wid + 16) * 32)      = tC;
            *(u32x4*)(rowp + (wid + 16) * 32 + 16) = (u32x4){0u, 0u, 0u, 0u};
        }
    }
    __syncthreads();

    f32x4 acc[4] = {};
    const int gk = lane >> 4;
    const int kt0 = (DEG == 0) ? 2 : 0;
#pragma unroll
    for (int kt = kt0; kt < 5; ++kt) {
        const unsigned short* wp = g_wfrag + ((size_t)(((DEG * 5 + kt) * 8 + wid) * 64 + lane)) * 16;
        const short8 wh = *(const short8*)wp;
        const short8 wl = *(const short8*)(wp + 8);
#pragma unroll
        for (int m = 0; m < 4; ++m) {
            const char* ab = A + (m * 16 + (lane & 15)) * ROWB + kt * 128 + gk * 32;
            const short8 ah = *(const short8*)ab;
            const short8 al = *(const short8*)(ab + 16);
            acc[m] = __builtin_amdgcn_mfma_f32_16x16x32_bf16(ah, wh, acc[m], 0, 0, 0);
            acc[m] = __builtin_amdgcn_mfma_f32_16x16x32_bf16(al, wh, acc[m], 0, 0, 0);
            acc[m] = __builtin_amdgcn_mfma_f32_16x16x32_bf16(ah, wl, acc[m], 0, 0, 0);
        }
    }

    const int col = wid * 16 + (lane & 15);
    const float bsum = (DEG > 0)
        ? (B[(size_t)(2 * (DEG - 1)) * HID + col] + B[(size_t)(2 * (DEG - 1) + 1) * HID + col])
        : B[(size_t)20 * HID + col];
    const float s  = bg[col] * rsqrtf(bv[col] + BN_EPS);
    const float sh = bb[col] - bm[col] * s;
#pragma unroll
    for (int m = 0; m < 4; ++m) {
#pragma unroll
        for (int j = 0; j < 4; ++j) {
            const int r = m * 16 + (lane >> 4) * 4 + j;
            if (r < nA) {
                const float val = fast_tanh(acc[m][j] + bsum) * s + sh;
                g_bn1b[(size_t)(atom0 + r) * 128 + col] = f2bf(val);
            }
        }
    }
}

__global__ __launch_bounds__(512, 6) void k_gc1(
    const float* __restrict__ B,
    const float* __restrict__ bg, const float* __restrict__ bb,
    const float* __restrict__ bm, const float* __restrict__ bv,
    AdjPtrs adj)
{
    // heavy-first: deg 10,9,...,1,0
    constexpr int TSH[12]    = {0,5,16,48,111,236,471,1253,2191,2816,3113,3129};
    constexpr int DEGORD[11] = {10,9,8,7,6,5,4,3,2,1,0};
    __shared__ __align__(16) char A[64 * ROWB];   // 41984 B -> 3 blocks/CU

    const int blk = blockIdx.x;
    int seg = 0;
#pragma unroll
    for (int s = 1; s <= 10; ++s) if (blk >= TSH[s]) seg = s;
    const int deg  = DEGORD[seg];
    const int tile = blk - TSH[seg];

    switch (deg) {
        case 0:  gc1_body<0 >(tile, A, B, bg, bb, bm, bv, nullptr);   break;
        case 1:  gc1_body<1 >(tile, A, B, bg, bb, bm, bv, adj.p[0]);  break;
        case 2:  gc1_body<2 >(tile, A, B, bg, bb, bm, bv, adj.p[1]);  break;
        case 3:  gc1_body<3 >(tile, A, B, bg, bb, bm, bv, adj.p[2]);  break;
        case 4:  gc1_body<4 >(tile, A, B, bg, bb, bm, bv, adj.p[3]);  break;
        case 5:  gc1_body<5 >(tile, A, B, bg, bb, bm, bv, adj.p[4]);  break;
        case 6:  gc1_body<6 >(tile, A, B, bg, bb, bm, bv, adj.p[5]);  break;
        case 7:  gc1_body<7 >(tile, A, B, bg, bb, bm, bv, adj.p[6]);  break;
        case 8:  gc1_body<8 >(tile, A, B, bg, bb, bm, bv, adj.p[7]);  break;
        case 9:  gc1_body<9 >(tile, A, B, bg, bb, bm, bv, adj.p[8]);  break;
        case 10: gc1_body<10>(tile, A, B, bg, bb, bm, bv, adj.p[9]);  break;
    }
}

// ---------------- K2: deterministic segment sum/max partials (u8 membership, bf16 bn1) ----------------
__global__ __launch_bounds__(128) void k_seg()
{
    const int b = blockIdx.x % NB;
    const int s = blockIdx.x / NB;
    const int aLo = s * SLEN;
    const int aHi = min(aLo + SLEN, 200000);
    const int wave = threadIdx.x >> 6;
    const int lane = threadIdx.x & 63;

    __shared__ int q[2][256];
    __shared__ int qn[2];
    int* myq = q[wave];
    int nq = 0;

    for (int base = aLo + wave * 64; base < aHi; base += 128) {
        const int a = base + lane;
        const bool m = (a < aHi) && (g_memb8[a] == (unsigned char)b);
        const unsigned long long bal = __ballot(m);
        if (m) {
            const int pos = __popcll(bal & ((1ull << lane) - 1ull));
            if (nq + pos < 256) myq[nq + pos] = a;
        }
        nq += __popcll(bal);
    }
    if (lane == 0) qn[wave] = min(nq, 256);
    __syncthreads();

    const int c = threadIdx.x;  // col 0..127
    float sum = 0.f, mx = -FLT_MAX;
#pragma unroll
    for (int w2 = 0; w2 < 2; ++w2) {
        const int n = qn[w2];
        for (int i = 0; i < n; ++i) {
            const float v = bf2f(g_bn1b[(size_t)q[w2][i] * 128 + c]);
            sum += v;
            mx = fmaxf(mx, v);
        }
    }
    float* pd = g_part + (size_t)(s * NB + b) * 256;
    pd[c] = sum;
    pd[128 + c] = mx;
}

// ---------------- K3: reduce partials (4-way chunked), tanh, dense, softmax ----------------
__global__ __launch_bounds__(1024) void k_final(const float* __restrict__ W2,
                                                const float* __restrict__ b2,
                                                float* __restrict__ out)
{
    const int b  = blockIdx.x;
    const int t  = threadIdx.x;
    const int c  = t & 255;
    const int cc = t >> 8;           // 0..3, each reduces 32 stripes
    __shared__ float red[4][256];
    __shared__ float ro[256];
    __shared__ float lg[24];

    {
        float v;
        if (c < 128) {
            float sv = 0.f;
            for (int s = cc * 32; s < cc * 32 + 32; ++s)
                sv += g_part[(size_t)(s * NB + b) * 256 + c];
            v = sv;
        } else {
            float mv = -FLT_MAX;
            for (int s = cc * 32; s < cc * 32 + 32; ++s)
                mv = fmaxf(mv, g_part[(size_t)(s * NB + b) * 256 + c]);
            v = mv;
        }
        red[cc][c] = v;
    }
    __syncthreads();
    if (cc == 0) {
        float v;
        if (c < 128) v = red[0][c] + red[1][c] + red[2][c] + red[3][c];
        else         v = fmaxf(fmaxf(red[0][c], red[1][c]), fmaxf(red[2][c], red[3][c]));
        ro[c] = tanhf(v);
    }
    __syncthreads();
    if (t < 24) {
        float acc = b2[t];
        for (int cx = 0; cx < 256; ++cx) acc = fmaf(ro[cx], W2[cx * 24 + t], acc);
        lg[t] = acc;
    }
    __syncthreads();
    if (t < NT) {
        const float l0 = lg[2 * t], l1 = lg[2 * t + 1];
        const float m = fmaxf(l0, l1);
        const float e0 = expf(l0 - m), e1 = expf(l1 - m);
        const float inv = 1.f / (e0 + e1);
        out[b * 24 + 2 * t]     = e0 * inv;
        out[b * 24 + 2 * t + 1] = e1 * inv;
    }
}

extern "C" void kernel_launch(void* const* d_in, const int* in_sizes, int n_in,
                              void* d_out, int out_size, void* d_ws, size_t ws_size,
                              hipStream_t stream) {
    const float* X    = (const float*)d_in[0];
    const int*   memb = (const int*)d_in[2];
    AdjPtrs adj;
    for (int d = 0; d < 10; ++d) adj.p[d] = (const int*)d_in[3 + d];
    const float* W1 = (const float*)d_in[13];
    const float* B1 = (const float*)d_in[14];
    const float* bg = (const float*)d_in[17];
    const float* bb = (const float*)d_in[18];
    const float* bm = (const float*)d_in[19];
    const float* bv = (const float*)d_in[20];
    const float* W2 = (const float*)d_in[31];
    const float* b2 = (const float*)d_in[32];
    float* out = (float*)d_out;

    k_pre<<<3761, 256, 0, stream>>>(W1, X, memb);
    k_gc1<<<3129, 512, 0, stream>>>(B1, bg, bb, bm, bv, adj);
    k_seg<<<NSEG * NB, 128, 0, stream>>>();
    k_final<<<NB, 1024, 0, stream>>>(W2, b2, out);
}